// Round 6
// baseline (184.858 us; speedup 1.0000x reference)
//
#include <hip/hip_runtime.h>

typedef unsigned short ushort_t;
typedef __attribute__((ext_vector_type(8))) short short8;
typedef __attribute__((ext_vector_type(4))) float f32x4;

#define DIMC 512
#define PN   32768                  // 8*64*64 spatial positions
#define SQRTC 22.627416997969522f   // sqrt(512)

__device__ __forceinline__ ushort_t f2bf(float f) {
  unsigned int u = __float_as_uint(f);
  unsigned int r = u + 0x7fffu + ((u >> 16) & 1u);   // round-to-nearest-even
  return (ushort_t)(r >> 16);
}
__device__ __forceinline__ unsigned int pack2(float lo, float hi) {
  return ((unsigned int)f2bf(hi) << 16) | (unsigned int)f2bf(lo);
}

typedef __attribute__((address_space(1))) unsigned int glb_u32;
typedef __attribute__((address_space(3))) unsigned int lds_u32;
__device__ __forceinline__ void gl_lds16(const ushort_t* g, ushort_t* l) {
  __builtin_amdgcn_global_load_lds((const glb_u32*)(g), (lds_u32*)(l), 16, 0, 0);
}

// ================= fused prep dispatcher: 656 blocks ==================
//  blocks [0,512)   : xT[p][c] = bf16(x[c][p]); s[p] = sqrt(512)/max(||x[:,p]||,1e-12)
//  blocks [512,528) : Mp[o][c] = bf16((sum_k wproj[o,k]*wqkv[1024+k,c]) * gamma[c])
//  blocks [528,656) : fb[o] = sum_k wproj[o,k]*bqkv[1024+k] + bproj[o]
__global__ __launch_bounds__(256) void k_prep(
    const float* __restrict__ x, const float* __restrict__ gamma,
    const float* __restrict__ wqkv, const float* __restrict__ bqkv,
    const float* __restrict__ wproj, const float* __restrict__ bproj,
    ushort_t* __restrict__ Mp, float* __restrict__ fb,
    float* __restrict__ s, ushort_t* __restrict__ xT) {
  __shared__ ushort_t uls[18944];          // 37888 B union of the three branches
  int bb = blockIdx.x;
  int tid = threadIdx.x;

  if (bb < 512) {
    // ---------- transpose + cast + norm ----------
    ushort_t* xt = uls;                    // 64 x 264 (row pad: conflicts + 16B align)
    float* red = (float*)(uls + 16896);    // 16 x 64
    long p0 = (long)bb * 64;
    int cg = tid >> 4;                     // 16 c-lanes
    int p4 = (tid & 15) * 4;               // 16 p-groups of 4
    float ss0 = 0.f, ss1 = 0.f, ss2 = 0.f, ss3 = 0.f;
    for (int half = 0; half < 2; ++half) {
      __syncthreads();                     // protect xt vs previous writeout
#pragma unroll 4
      for (int pass = 0; pass < 16; ++pass) {
        int cl = pass * 16 + cg;           // local col 0..255
        int c = half * 256 + cl;
        float4 v = *(const float4*)(x + (long)c * PN + p0 + p4);
        xt[(p4 + 0) * 264 + cl] = f2bf(v.x);
        xt[(p4 + 1) * 264 + cl] = f2bf(v.y);
        xt[(p4 + 2) * 264 + cl] = f2bf(v.z);
        xt[(p4 + 3) * 264 + cl] = f2bf(v.w);
        ss0 += v.x * v.x; ss1 += v.y * v.y; ss2 += v.z * v.z; ss3 += v.w * v.w;
      }
      __syncthreads();
#pragma unroll
      for (int i = 0; i < 8; ++i) {
        int chunk = tid + i * 256;
        int r = chunk >> 5;                // 32 chunks per row
        int c8 = (chunk & 31) * 8;
        uint4 v = *(const uint4*)(&xt[r * 264 + c8]);
        *(uint4*)(xT + (p0 + r) * DIMC + half * 256 + c8) = v;
      }
    }
    red[cg * 64 + p4 + 0] = ss0;
    red[cg * 64 + p4 + 1] = ss1;
    red[cg * 64 + p4 + 2] = ss2;
    red[cg * 64 + p4 + 3] = ss3;
    __syncthreads();
    if (tid < 64) {
      float t = 0.f;
#pragma unroll
      for (int g = 0; g < 16; ++g) t += red[g * 64 + tid];
      s[p0 + tid] = SQRTC / fmaxf(sqrtf(t), 1e-12f);
    }

  } else if (bb < 528) {
    // ---------- weight GEMM (round-3-proven template, f32 inputs) ----------
    ushort_t* As = uls;                    // [o][64k]
    ushort_t* Bs = uls + 8192;             // [k][128c]
    const float* A = wproj;
    const float* B = wqkv + 1024 * DIMC;
    int bidx = bb - 512;
    int p0 = (bidx & 3) * 128;
    int o0 = (bidx >> 2) * 128;
    int wave = tid >> 6, lane = tid & 63;
    int wo = (wave & 1) * 64, wp = (wave >> 1) * 64;
    int q = lane >> 4, ln = lane & 15;
    f32x4 zero = {0.f, 0.f, 0.f, 0.f};
    f32x4 acc[4][4];
#pragma unroll
    for (int i = 0; i < 4; ++i)
#pragma unroll
      for (int j = 0; j < 4; ++j) acc[i][j] = zero;
    int ar = tid >> 3, ac = (tid & 7) * 8;
    int br = tid >> 4, bc = (tid & 15) * 8;
    for (int kc = 0; kc < DIMC; kc += 64) {
      __syncthreads();
#pragma unroll
      for (int it = 0; it < 4; ++it) {
        int r = ar + it * 32;
        const float* ap = A + (long)(o0 + r) * DIMC + kc + ac;
        float4 a0 = *(const float4*)ap;
        float4 a1 = *(const float4*)(ap + 4);
        uint4 wa;
        wa.x = pack2(a0.x, a0.y); wa.y = pack2(a0.z, a0.w);
        wa.z = pack2(a1.x, a1.y); wa.w = pack2(a1.z, a1.w);
        *(uint4*)(&As[r * 64 + ac]) = wa;
        int kr = br + it * 16;
        const float* bp = B + (long)(kc + kr) * DIMC + p0 + bc;
        float4 b0 = *(const float4*)bp;
        float4 b1 = *(const float4*)(bp + 4);
        uint4 wb;
        wb.x = pack2(b0.x, b0.y); wb.y = pack2(b0.z, b0.w);
        wb.z = pack2(b1.x, b1.y); wb.w = pack2(b1.z, b1.w);
        *(uint4*)(&Bs[kr * 128 + bc]) = wb;
      }
      __syncthreads();
#pragma unroll
      for (int ks = 0; ks < 2; ++ks) {
        int kb = ks * 32 + q * 8;
        short8 af[4], bfr[4];
#pragma unroll
        for (int mi = 0; mi < 4; ++mi)
          af[mi] = *(const short8*)(&As[(wo + mi * 16 + ln) * 64 + kb]);
#pragma unroll
        for (int ni = 0; ni < 4; ++ni) {
          int pl = wp + ni * 16 + ln;
          short8 t;
#pragma unroll
          for (int j = 0; j < 8; ++j) t[j] = (short)Bs[(kb + j) * 128 + pl];
          bfr[ni] = t;
        }
#pragma unroll
        for (int mi = 0; mi < 4; ++mi)
#pragma unroll
          for (int ni = 0; ni < 4; ++ni)
            acc[mi][ni] = __builtin_amdgcn_mfma_f32_16x16x32_bf16(af[mi], bfr[ni], acc[mi][ni], 0, 0, 0);
      }
    }
#pragma unroll
    for (int mi = 0; mi < 4; ++mi) {
      int obase = o0 + wo + mi * 16 + q * 4;
#pragma unroll
      for (int ni = 0; ni < 4; ++ni) {
        int p = p0 + wp + ni * 16 + ln;
        float g = gamma[p];
#pragma unroll
        for (int r = 0; r < 4; ++r)
          Mp[(long)(obase + r) * DIMC + p] = f2bf(acc[mi][ni][r] * g);
      }
    }

  } else {
    // ---------- fused bias ----------
    int wave = tid >> 6;
    int lane = tid & 63;
    int o = (bb - 528) * 4 + wave;         // 128 blocks -> o in [0,512)
    float part = 0.f;
#pragma unroll
    for (int i = 0; i < 8; ++i) {
      int k = lane + i * 64;
      part += wproj[o * DIMC + k] * bqkv[1024 + k];
    }
    for (int off = 32; off; off >>= 1) part += __shfl_down(part, off, 64);
    if (lane == 0) fb[o] = part + bproj[o];
  }
}

// ================= main MFMA GEMM =================
// out[o][p] = xid[o][p] + fb[o] + s[p] * sum_c Mp[o,c]*xT[p,c]
// global_load_lds staging (WAVE-UNIFORM lds base; source XOR swizzle) +
// barriered LDS-transpose epilogue with float4 global I/O.
__global__ __launch_bounds__(256) void k_main(
    const ushort_t* __restrict__ A,    // Mp [512][512] bf16
    const ushort_t* __restrict__ BT,   // xT [32768][512] bf16
    float* __restrict__ C,
    const float* __restrict__ xid,
    const float* __restrict__ fb,
    const float* __restrict__ s) {
  __shared__ ushort_t smem[2 * 128 * 64];   // 32 KB: As | Bs, reused as f32 scratch in epilogue
  ushort_t* As = smem;
  ushort_t* Bs = smem + 128 * 64;
  int tid = threadIdx.x;
  int p0 = blockIdx.x * 128;
  int o0 = blockIdx.y * 128;
  int wave = tid >> 6, lane = tid & 63;
  int wo = (wave & 1) * 64, wp = (wave >> 1) * 64;
  int q = lane >> 4, ln = lane & 15;

  f32x4 zero = {0.f, 0.f, 0.f, 0.f};
  f32x4 acc[4][4];
#pragma unroll
  for (int i = 0; i < 4; ++i)
#pragma unroll
    for (int j = 0; j < 4; ++j) acc[i][j] = zero;

  int lr = lane >> 3;            // row 0..7 within the wave's 8-row stage block
  int lc = lane & 7;             // dest chunk slot (position lane lands at: base+16*lane)
  int csw = lc ^ lr;             // swizzled SOURCE chunk -> slot lc holds chunk lc^(row&7)

  for (int kc = 0; kc < DIMC; kc += 64) {
    __syncthreads();
#pragma unroll
    for (int it = 0; it < 4; ++it) {
      int rb = (it * 4 + wave) * 8;              // wave-uniform tile row base
      // HW writes lane i at &As[rb*64] + 16*i == row rb+(i>>3), slot i&7. Source
      // address carries the per-lane row (lr) and swizzled chunk (csw).
      gl_lds16(A  + (long)(o0 + rb + lr) * DIMC + kc + csw * 8, &As[rb * 64]);
      gl_lds16(BT + (long)(p0 + rb + lr) * DIMC + kc + csw * 8, &Bs[rb * 64]);
    }
    asm volatile("s_waitcnt vmcnt(0)" ::: "memory");   // explicit DMA drain
    __syncthreads();
#pragma unroll
    for (int ks = 0; ks < 2; ++ks) {
      int cch = ks * 4 + q;                      // logical 16B chunk 0..7
      short8 af[4], bf[4];
#pragma unroll
      for (int mi = 0; mi < 4; ++mi) {
        int row = wo + mi * 16 + ln;
        af[mi] = *(const short8*)(&As[row * 64 + ((cch ^ (row & 7)) * 8)]);
      }
#pragma unroll
      for (int ni = 0; ni < 4; ++ni) {
        int row = wp + ni * 16 + ln;
        bf[ni] = *(const short8*)(&Bs[row * 64 + ((cch ^ (row & 7)) * 8)]);
      }
#pragma unroll
      for (int mi = 0; mi < 4; ++mi)
#pragma unroll
        for (int ni = 0; ni < 4; ++ni)
          acc[mi][ni] = __builtin_amdgcn_mfma_f32_16x16x32_bf16(af[mi], bf[ni], acc[mi][ni], 0, 0, 0);
    }
  }

  // ---- epilogue: per-wave 16(o) x 64(p) f32 transpose through LDS (barriered),
  //      then float4 identity-add and store.
  float* scr = (float*)smem + wave * 1088;       // 16 rows x 68 stride (16B-aligned rows)
  float4 s4 = *(const float4*)(s + p0 + wp + ln * 4);
#pragma unroll
  for (int mi = 0; mi < 4; ++mi) {
    __syncthreads();                             // prior reads (or K-loop) done before overwrite
#pragma unroll
    for (int ni = 0; ni < 4; ++ni)
#pragma unroll
      for (int r = 0; r < 4; ++r)
        scr[(q * 4 + r) * 68 + ni * 16 + ln] = acc[mi][ni][r];
    __syncthreads();                             // all lanes' writes visible
    int ob = o0 + wo + mi * 16 + q;
    int p = p0 + wp + ln * 4;
#pragma unroll
    for (int j = 0; j < 4; ++j) {
      int o = ob + j * 4;
      float4 d = *(const float4*)(&scr[(q + j * 4) * 68 + ln * 4]);
      float4 xv = *(const float4*)(xid + (long)o * PN + p);
      float fbv = fb[o];
      float4 ov;
      ov.x = xv.x + fbv + s4.x * d.x;
      ov.y = xv.y + fbv + s4.y * d.y;
      ov.z = xv.z + fbv + s4.z * d.z;
      ov.w = xv.w + fbv + s4.w * d.w;
      *(float4*)(C + (long)o * PN + p) = ov;
    }
  }
}

extern "C" void kernel_launch(void* const* d_in, const int* in_sizes, int n_in,
                              void* d_out, int out_size, void* d_ws, size_t ws_size,
                              hipStream_t stream) {
  const float* x     = (const float*)d_in[0];
  const float* gamma = (const float*)d_in[1];
  const float* wqkv  = (const float*)d_in[2];
  const float* bqkv  = (const float*)d_in[3];
  const float* wproj = (const float*)d_in[4];
  const float* bproj = (const float*)d_in[5];

  char* ws = (char*)d_ws;
  ushort_t* Mp = (ushort_t*)(ws);              // 512*512 bf16
  float*    fb = (float*)(ws + 524288);        // 512 f32
  float*    s  = (float*)(ws + 526336);        // 32768 f32
  ushort_t* xT = (ushort_t*)(ws + 2097152);    // 32768*512 bf16 (32 MB)

  k_prep<<<dim3(656), dim3(256), 0, stream>>>(x, gamma, wqkv, bqkv, wproj, bproj,
                                              Mp, fb, s, xT);
  k_main<<<dim3(256, 4), dim3(256), 0, stream>>>(Mp, xT, (float*)d_out, x, fb, s);
}